// Round 1
// baseline (809.546 us; speedup 1.0000x reference)
//
#include <hip/hip_runtime.h>
#include <hip/hip_bf16.h>

// Problem constants (from reference)
#define B_  2
#define F_  2
#define C_  64
#define D_  96
#define HM_ 48
#define WM_ 160
#define HW_ (HM_ * WM_)          // 7680
#define NTOT ((size_t)B_ * D_ * HW_)   // 1,474,560 per output tensor
#define EPS_ 1e-7f

// ---------------------------------------------------------------------------
// Transpose [N][C=64][HW] -> [N][HW][C=64], tiled 64x64 via LDS (padded).
// grid: N * (HW/64) blocks, 256 threads.
// ---------------------------------------------------------------------------
__global__ __launch_bounds__(256) void transpose_chw_hwc(
    const float* __restrict__ in, float* __restrict__ out, int tiles_per_img)
{
    __shared__ float tile[64][65];
    int tb = blockIdx.x;
    int n   = tb / tiles_per_img;
    int hw0 = (tb % tiles_per_img) * 64;
    int tx = threadIdx.x & 63;   // inner (coalesced) index
    int ty = threadIdx.x >> 6;   // 0..3

    const float* src = in + (size_t)n * C_ * HW_;
    #pragma unroll
    for (int c = ty; c < 64; c += 4)
        tile[c][tx] = src[(size_t)c * HW_ + hw0 + tx];
    __syncthreads();
    float* dst = out + ((size_t)n * HW_ + hw0) * 64;
    #pragma unroll
    for (int hwi = ty; hwi < 64; hwi += 4)
        dst[(size_t)hwi * 64 + tx] = tile[tx][hwi];
}

// ---------------------------------------------------------------------------
// Precompute P = (K @ T)[:3] per (b,f) (12 floats each) and pose validity.
// Single block of 64 threads.
// ---------------------------------------------------------------------------
__global__ void setup_proj(const float* __restrict__ poses,
                           const float* __restrict__ K,
                           float* __restrict__ Pout,      // [B*F][12]
                           float* __restrict__ validOut)  // [B*F]
{
    int t = threadIdx.x;
    if (t < B_ * F_ * 12) {
        int j  = t & 3;
        int i  = (t >> 2) % 3;
        int bf = t / 12;
        int b  = bf / F_;
        const float* Kb = K + (size_t)b * 16;
        const float* T  = poses + (size_t)bf * 16;
        float s = 0.f;
        #pragma unroll
        for (int k = 0; k < 4; ++k) s += Kb[i * 4 + k] * T[k * 4 + j];
        Pout[bf * 12 + i * 4 + j] = s;
    }
    if (t < B_ * F_) {
        const float* T = poses + (size_t)t * 16;
        float s = 0.f;
        #pragma unroll
        for (int k = 0; k < 16; ++k) s += T[k];
        validOut[t] = (s != 0.0f) ? 1.0f : 0.0f;
    }
}

// ---------------------------------------------------------------------------
// Main cost-volume kernel. One wave (64 lanes) per (b,d,hw); lane = channel.
// Writes pre-fill cost (== cv_feature) to cvOut [B][D][HW].
// ---------------------------------------------------------------------------
__global__ __launch_bounds__(256) void cost_volume(
    const float* __restrict__ curT,    // [B][HW][64]
    const float* __restrict__ lookT,   // [B*F][HW][64]
    const float* __restrict__ invK,    // [B][16]
    const float* __restrict__ P,       // [B*F][12]
    const float* __restrict__ validF,  // [B*F]
    float* __restrict__ cvOut)         // [B][D][HW]
{
    int wid  = blockIdx.x * 4 + (threadIdx.x >> 6);
    int lane = threadIdx.x & 63;

    int hw   = wid % HW_;
    int rest = wid / HW_;
    int d    = rest % D_;
    int b    = rest / D_;

    int x = hw % WM_, y = hw / WM_;
    float fx = (float)x, fy = (float)y;

    const float* ik = invK + (size_t)b * 16;
    float rx = ik[0] * fx + ik[1] * fy + ik[2];
    float ry = ik[4] * fx + ik[5] * fy + ik[6];
    float rz = ik[8] * fx + ik[9] * fy + ik[10];

    float depth = 0.1f + (float)d * (19.9f / 95.0f);
    float qx = depth * rx, qy = depth * ry, qz = depth * rz;

    float curv = curT[((size_t)b * HW_ + hw) * 64 + lane];
    bool inter = (x >= 2 && x <= WM_ - 3 && y >= 2 && y <= HM_ - 3);

    float costsum = 0.f, counts = 0.f;

    #pragma unroll
    for (int f = 0; f < F_; ++f) {
        const float* Pf = P + (size_t)(b * F_ + f) * 12;
        float cp0 = Pf[0] * qx + Pf[1] * qy + Pf[2]  * qz + Pf[3];
        float cp1 = Pf[4] * qx + Pf[5] * qy + Pf[6]  * qz + Pf[7];
        float cp2 = Pf[8] * qx + Pf[9] * qy + Pf[10] * qz + Pf[11];
        float z  = cp2 + EPS_;
        float gx = cp0 / z, gy = cp1 / z;

        float x0 = floorf(gx), y0 = floorf(gy);
        float wx1 = gx - x0, wy1 = gy - y0;
        float wx0 = 1.f - wx1, wy0 = 1.f - wy1;

        const float* base = lookT + (size_t)(b * F_ + f) * HW_ * 64;

        float acc = 0.f;
        {   // 4 bilinear corners, zero-padding semantics
            float cxs[4] = {x0, x0 + 1.f, x0,        x0 + 1.f};
            float cys[4] = {y0, y0,       y0 + 1.f,  y0 + 1.f};
            float ws[4]  = {wx0 * wy0, wx1 * wy0, wx0 * wy1, wx1 * wy1};
            #pragma unroll
            for (int cn = 0; cn < 4; ++cn) {
                float cxf = cxs[cn], cyf = cys[cn];
                bool v = (cxf >= 0.f) & (cxf <= (float)(WM_ - 1)) &
                         (cyf >= 0.f) & (cyf <= (float)(HM_ - 1));
                float cxc = fminf(fmaxf(cxf, 0.f), (float)(WM_ - 1));
                float cyc = fminf(fmaxf(cyf, 0.f), (float)(HM_ - 1));
                int idx = (int)cyc * WM_ + (int)cxc;
                float val = base[(size_t)idx * 64 + lane];
                acc += val * (v ? ws[cn] : 0.f);
            }
        }

        float a = fabsf(acc - curv);
        // full-wave (64-lane) butterfly sum
        #pragma unroll
        for (int off = 32; off; off >>= 1)
            a += __shfl_xor(a, off);
        float meanc = a * (1.0f / 64.0f);

        bool e = (gx >= 2.f) && (gx <= (float)(WM_ - 2)) &&
                 (gy >= 2.f) && (gy <= (float)(HM_ - 2)) && inter;

        float diff = meanc * (e ? 1.f : 0.f) * validF[b * F_ + f];
        costsum += diff;
        counts  += (diff > 0.f) ? 1.f : 0.f;
    }

    if (lane == 0) {
        float cost_pre = costsum / (counts + EPS_);
        cvOut[(size_t)wid] = cost_pre;
    }
}

// ---------------------------------------------------------------------------
// Finalize: per (b,hw), max over D, then write cost / missing.
// cv region already holds pre-fill cost (== cv_feature output).
// ---------------------------------------------------------------------------
__global__ __launch_bounds__(256) void finalize(
    const float* __restrict__ cv,   // [B][D][HW]
    float* __restrict__ cost,       // [B][D][HW]
    float* __restrict__ missing)    // [B][D][HW]
{
    int t = blockIdx.x * blockDim.x + threadIdx.x;
    if (t >= B_ * HW_) return;
    int b = t / HW_, hw = t % HW_;
    const float* src = cv + (size_t)b * D_ * HW_ + hw;

    float mx = 0.f;   // all values >= 0
    for (int d = 0; d < D_; ++d)
        mx = fmaxf(mx, src[(size_t)d * HW_]);

    for (int d = 0; d < D_; ++d) {
        float v = src[(size_t)d * HW_];
        float m = (v == 0.f) ? 1.f : 0.f;
        size_t o = (size_t)b * D_ * HW_ + (size_t)d * HW_ + hw;
        cost[o]    = (m != 0.f) ? mx : v;
        missing[o] = m;
    }
}

// ---------------------------------------------------------------------------
extern "C" void kernel_launch(void* const* d_in, const int* in_sizes, int n_in,
                              void* d_out, int out_size, void* d_ws, size_t ws_size,
                              hipStream_t stream)
{
    const float* current = (const float*)d_in[0];  // [B,C,H,W]
    const float* lookup  = (const float*)d_in[1];  // [B,F,C,H,W]
    const float* poses   = (const float*)d_in[2];  // [B,F,4,4]
    const float* K       = (const float*)d_in[3];  // [B,4,4]
    const float* invK    = (const float*)d_in[4];  // [B,4,4]

    float* out = (float*)d_out;
    float* costOut    = out;                 // [B,D,H,W]
    float* missingOut = out + NTOT;          // [B,D,H,W]
    float* cvOut      = out + 2 * NTOT;      // [B,D,H,W] (pre-fill cost)

    // workspace layout (floats)
    float* ws     = (float*)d_ws;
    float* curT   = ws;                                   // B*HW*64      = 983040
    float* lookT  = curT + (size_t)B_ * HW_ * 64;         // B*F*HW*64    = 1966080
    float* Pmat   = lookT + (size_t)B_ * F_ * HW_ * 64;   // B*F*12       = 48
    float* validF = Pmat + B_ * F_ * 12;                  // B*F          = 4

    const int tiles = HW_ / 64;  // 120

    hipLaunchKernelGGL(transpose_chw_hwc, dim3(B_ * tiles), dim3(256), 0, stream,
                       current, curT, tiles);
    hipLaunchKernelGGL(transpose_chw_hwc, dim3(B_ * F_ * tiles), dim3(256), 0, stream,
                       lookup, lookT, tiles);
    hipLaunchKernelGGL(setup_proj, dim3(1), dim3(64), 0, stream,
                       poses, K, Pmat, validF);

    const int total_waves = B_ * D_ * HW_;      // 1,474,560
    hipLaunchKernelGGL(cost_volume, dim3(total_waves / 4), dim3(256), 0, stream,
                       curT, lookT, invK, Pmat, validF, cvOut);

    const int npix = B_ * HW_;                  // 15,360
    hipLaunchKernelGGL(finalize, dim3((npix + 255) / 256), dim3(256), 0, stream,
                       cvOut, costOut, missingOut);
}

// Round 2
// 141.077 us; speedup vs baseline: 5.7383x; 5.7383x over previous
//
#include <hip/hip_runtime.h>
#include <hip/hip_bf16.h>

// Problem constants (from reference)
#define B_  2
#define F_  2
#define C_  64
#define D_  96
#define HM_ 48
#define WM_ 160
#define HW_ (HM_ * WM_)                 // 7680
#define NTOT ((size_t)B_ * D_ * HW_)    // 1,474,560 per output tensor
#define EPS_ 1e-7f

// ---------------------------------------------------------------------------
// Precompute P = (K @ T)[:3] per (b,f) (12 floats each) and pose validity.
// Single block of 64 threads.
// ---------------------------------------------------------------------------
__global__ void setup_proj(const float* __restrict__ poses,
                           const float* __restrict__ K,
                           float* __restrict__ Pout,      // [B*F][12]
                           float* __restrict__ validOut)  // [B*F]
{
    int t = threadIdx.x;
    if (t < B_ * F_ * 12) {
        int j  = t & 3;
        int i  = (t >> 2) % 3;
        int bf = t / 12;
        int b  = bf / F_;
        const float* Kb = K + (size_t)b * 16;
        const float* T  = poses + (size_t)bf * 16;
        float s = 0.f;
        #pragma unroll
        for (int k = 0; k < 4; ++k) s += Kb[i * 4 + k] * T[k * 4 + j];
        Pout[bf * 12 + i * 4 + j] = s;
    }
    if (t < B_ * F_) {
        const float* T = poses + (size_t)t * 16;
        float s = 0.f;
        #pragma unroll
        for (int k = 0; k < 16; ++k) s += T[k];
        validOut[t] = (s != 0.0f) ? 1.0f : 0.0f;
    }
}

// ---------------------------------------------------------------------------
// Main cost-volume kernel. ONE THREAD per output (b,d,hw); channel loop in
// registers. Original [C][HW] layout: per-channel loads are coalesced across
// lanes (adjacent lanes = adjacent pixels -> near-unit-stride corner offsets).
// Writes pre-fill cost (== cv_feature) to cvOut [B][D][HW].
// ---------------------------------------------------------------------------
__global__ __launch_bounds__(256) void cost_volume(
    const float* __restrict__ cur,     // [B][C][HW]
    const float* __restrict__ look,    // [B][F][C][HW]
    const float* __restrict__ invK,    // [B][16]
    const float* __restrict__ P,       // [B*F][12]
    const float* __restrict__ validF,  // [B*F]
    float* __restrict__ cvOut)         // [B][D][HW]
{
    int gid  = blockIdx.x * 256 + threadIdx.x;   // exact: B*D*HW = 5760*256
    int hw   = gid % HW_;
    int rest = gid / HW_;
    int d    = rest % D_;
    int b    = rest / D_;

    int x = hw % WM_, y = hw / WM_;
    float fx = (float)x, fy = (float)y;

    const float* ik = invK + (size_t)b * 16;
    float rx = ik[0] * fx + ik[1] * fy + ik[2];
    float ry = ik[4] * fx + ik[5] * fy + ik[6];
    float rz = ik[8] * fx + ik[9] * fy + ik[10];

    float depth = 0.1f + (float)d * (19.9f / 95.0f);
    float qx = depth * rx, qy = depth * ry, qz = depth * rz;

    bool inter = (x >= 2 && x <= WM_ - 3 && y >= 2 && y <= HM_ - 3);

    // Per-frame projection, bilinear weights, corner offsets (channel-invariant)
    float w[F_][4];      // bilinear weights (zeroed when corner OOB)
    int   off[F_][4];    // offsets into look[] for channel 0
    float factor[F_];    // edge * valid

    #pragma unroll
    for (int f = 0; f < F_; ++f) {
        const float* Pf = P + (size_t)(b * F_ + f) * 12;
        float cp0 = Pf[0] * qx + Pf[1] * qy + Pf[2]  * qz + Pf[3];
        float cp1 = Pf[4] * qx + Pf[5] * qy + Pf[6]  * qz + Pf[7];
        float cp2 = Pf[8] * qx + Pf[9] * qy + Pf[10] * qz + Pf[11];
        float z  = cp2 + EPS_;
        float gx = cp0 / z, gy = cp1 / z;

        float x0f = floorf(gx), y0f = floorf(gy);
        float wx1 = gx - x0f, wy1 = gy - y0f;
        float wx0 = 1.f - wx1, wy0 = 1.f - wy1;

        int x0 = (int)x0f, y0 = (int)y0f;      // cvt saturates on inf; fine
        int x1 = x0 + 1,  y1 = y0 + 1;
        bool vx0 = (x0 >= 0) && (x0 <= WM_ - 1);
        bool vx1 = (x1 >= 0) && (x1 <= WM_ - 1);
        bool vy0 = (y0 >= 0) && (y0 <= HM_ - 1);
        bool vy1 = (y1 >= 0) && (y1 <= HM_ - 1);

        int cx0 = min(max(x0, 0), WM_ - 1), cx1 = min(max(x1, 0), WM_ - 1);
        int cy0 = min(max(y0, 0), HM_ - 1), cy1 = min(max(y1, 0), HM_ - 1);

        int fb = (b * F_ + f) * C_ * HW_;      // frame base (channel 0)
        off[f][0] = fb + cy0 * WM_ + cx0;
        off[f][1] = fb + cy0 * WM_ + cx1;
        off[f][2] = fb + cy1 * WM_ + cx0;
        off[f][3] = fb + cy1 * WM_ + cx1;

        w[f][0] = wx0 * wy0 * ((vx0 && vy0) ? 1.f : 0.f);
        w[f][1] = wx1 * wy0 * ((vx1 && vy0) ? 1.f : 0.f);
        w[f][2] = wx0 * wy1 * ((vx0 && vy1) ? 1.f : 0.f);
        w[f][3] = wx1 * wy1 * ((vx1 && vy1) ? 1.f : 0.f);

        bool e = (gx >= 2.f) && (gx <= (float)(WM_ - 2)) &&
                 (gy >= 2.f) && (gy <= (float)(HM_ - 2)) && inter;
        factor[f] = (e ? 1.f : 0.f) * validF[b * F_ + f];
    }

    // Wave-uniform early-out: nothing contributes anywhere in this wave.
    if (__ballot(factor[0] > 0.f || factor[1] > 0.f) == 0ull) {
        cvOut[(size_t)gid] = 0.f;
        return;
    }

    int cb = b * C_ * HW_ + hw;   // current-feature base (channel 0)

    float s0 = 0.f, s1 = 0.f;
    int co = 0;
    #pragma unroll 4
    for (int c = 0; c < C_; ++c, co += HW_) {
        float cv_ = cur[cb + co];
        float a0 = w[0][0] * look[off[0][0] + co] + w[0][1] * look[off[0][1] + co]
                 + w[0][2] * look[off[0][2] + co] + w[0][3] * look[off[0][3] + co];
        float a1 = w[1][0] * look[off[1][0] + co] + w[1][1] * look[off[1][1] + co]
                 + w[1][2] * look[off[1][2] + co] + w[1][3] * look[off[1][3] + co];
        s0 += fabsf(a0 - cv_);
        s1 += fabsf(a1 - cv_);
    }

    float m0 = s0 * (1.0f / 64.0f) * factor[0];
    float m1 = s1 * (1.0f / 64.0f) * factor[1];
    float costsum = m0 + m1;
    float counts  = ((m0 > 0.f) ? 1.f : 0.f) + ((m1 > 0.f) ? 1.f : 0.f);
    cvOut[(size_t)gid] = costsum / (counts + EPS_);
}

// ---------------------------------------------------------------------------
// Finalize: per (b,hw), max over D, then write cost / missing.
// cv region already holds pre-fill cost (== cv_feature output).
// ---------------------------------------------------------------------------
__global__ __launch_bounds__(256) void finalize(
    const float* __restrict__ cv,   // [B][D][HW]
    float* __restrict__ cost,       // [B][D][HW]
    float* __restrict__ missing)    // [B][D][HW]
{
    int t = blockIdx.x * blockDim.x + threadIdx.x;
    if (t >= B_ * HW_) return;
    int b = t / HW_, hw = t % HW_;
    const float* src = cv + (size_t)b * D_ * HW_ + hw;

    float mx = 0.f;   // all values >= 0
    for (int d = 0; d < D_; ++d)
        mx = fmaxf(mx, src[(size_t)d * HW_]);

    for (int d = 0; d < D_; ++d) {
        float v = src[(size_t)d * HW_];
        float m = (v == 0.f) ? 1.f : 0.f;
        size_t o = (size_t)b * D_ * HW_ + (size_t)d * HW_ + hw;
        cost[o]    = (m != 0.f) ? mx : v;
        missing[o] = m;
    }
}

// ---------------------------------------------------------------------------
extern "C" void kernel_launch(void* const* d_in, const int* in_sizes, int n_in,
                              void* d_out, int out_size, void* d_ws, size_t ws_size,
                              hipStream_t stream)
{
    const float* current = (const float*)d_in[0];  // [B,C,H,W]
    const float* lookup  = (const float*)d_in[1];  // [B,F,C,H,W]
    const float* poses   = (const float*)d_in[2];  // [B,F,4,4]
    const float* K       = (const float*)d_in[3];  // [B,4,4]
    const float* invK    = (const float*)d_in[4];  // [B,4,4]

    float* out = (float*)d_out;
    float* costOut    = out;                 // [B,D,H,W]
    float* missingOut = out + NTOT;          // [B,D,H,W]
    float* cvOut      = out + 2 * NTOT;      // [B,D,H,W] (pre-fill cost)

    // workspace layout (floats)
    float* ws     = (float*)d_ws;
    float* Pmat   = ws;                      // B*F*12 = 48
    float* validF = Pmat + B_ * F_ * 12;     // B*F    = 4

    hipLaunchKernelGGL(setup_proj, dim3(1), dim3(64), 0, stream,
                       poses, K, Pmat, validF);

    const int total = B_ * D_ * HW_;            // 1,474,560 = 5760 * 256
    hipLaunchKernelGGL(cost_volume, dim3(total / 256), dim3(256), 0, stream,
                       current, lookup, invK, Pmat, validF, cvOut);

    const int npix = B_ * HW_;                  // 15,360
    hipLaunchKernelGGL(finalize, dim3((npix + 255) / 256), dim3(256), 0, stream,
                       cvOut, costOut, missingOut);
}